// Round 3
// baseline (201.217 us; speedup 1.0000x reference)
//
#include <hip/hip_runtime.h>
#include <math.h>

#define NQ  12
#define TPB 256

typedef __attribute__((ext_vector_type(2))) float f2;

// ================= compile-time GF(2) machinery (r8-validated) =================
// Folded space: gate q,layer l pairs x <-> x^v, role=parity(r&x), r_j.v_i=delta_ij.
// PAIRED passes (2m,2m+1) share lane basis B[0..7]; intra-pair transition is a
// wave-internal ds_bpermute (slot relabel sz, lane-xor gx). Boundary m: layout
// elem = sigma(Tp x); writes 8 contiguous swizzled b128, next-pair reads 16
// conflict-floor b64 (residues engineered through the boundary map).
// r11: two-element ping-pong per block (grid 2048). While element A's exchange
// is in flight (write, sync, read), element B's ~1200-cycle gate block runs ->
// barrier/lgkm idle filled in-block. A parks in LDS during B's compute, so S/Sn
// registers are SHARED between elements (liveness disjoint along the 12
// half-step schedule). Restores r8 exchange verbatim: 8xb128 writes + 16xb64
// engineered-residue reads, 2 barriers/exchange, 32KiB buffer.
// Occupancy: VGPR ~96-128 -> 4 waves/SIMD -> 4 blocks/CU x 2 elem = 8 elem/CU.

struct GF12 { unsigned row[12]; };

constexpr GF12 gf_id(){ GF12 m{}; for(int i=0;i<12;i++) m.row[i]=1u<<i; return m; }
constexpr GF12 gf_mul(const GF12&A,const GF12&B){
  GF12 r{};
  for(int i=0;i<12;i++){ unsigned acc=0;
    for(int k=0;k<12;k++) if((A.row[i]>>k)&1u) acc ^= B.row[k];
    r.row[i]=acc; }
  return r;
}
constexpr unsigned gf_apply(const GF12&A, unsigned x){
  unsigned y=0;
  for(int i=0;i<12;i++) y |= (unsigned)(__builtin_popcount(A.row[i]&x)&1)<<i;
  return y;
}
constexpr GF12 gf_cnot(int q){ GF12 m=gf_id(); int c=11-q, t=11-((q+1)%12); m.row[t]^=(1u<<c); return m; }
constexpr GF12 gf_inv(const GF12&A){
  unsigned a[12], inv[12];
  for(int i=0;i<12;i++){ a[i]=A.row[i]; inv[i]=1u<<i; }
  for(int c=0;c<12;c++){
    int p=-1;
    for(int r2=c;r2<12;r2++) if((a[r2]>>c)&1u){p=r2;break;}
    if(p<0) continue;
    unsigned ta=a[c]; a[c]=a[p]; a[p]=ta;
    unsigned ti=inv[c]; inv[c]=inv[p]; inv[p]=ti;
    for(int r2=0;r2<12;r2++) if(r2!=c && ((a[r2]>>c)&1u)){ a[r2]^=a[c]; inv[r2]^=inv[c]; }
  }
  GF12 R{}; for(int i=0;i<12;i++) R.row[i]=inv[i];
  return R;
}

struct Red { unsigned arr[12]; int hb[12]; int n; };
constexpr unsigned red_reduce(const Red& R, unsigned y){
  for(int i=0;i<R.n;i++) if((y>>R.hb[i])&1u) y ^= R.arr[i];
  return y;
}
constexpr bool red_add(Red& R, unsigned cand){
  unsigned y = red_reduce(R, cand);
  if(!y) return false;
  int h=0;
  for(int b2=11;b2>=1;b2--) if((y>>b2)&1u){ h=b2; break; }
  R.arr[R.n]=y; R.hb[R.n]=h; R.n++;
  return true;
}

struct PairT {
  unsigned M0[4], M1[4];
  unsigned sz[16], gx[16];
  unsigned rB[8], roff[16];
};
struct AllT { PairT pr[6]; unsigned mq[12], uq[12]; bool ok; };

constexpr AllT makeAll(){
  AllT T{}; T.ok=true;
  GF12 D=gf_id(); for(int q=0;q<12;q++) D=gf_mul(gf_cnot(q),D);
  GF12 Cm=gf_id(); for(int q=11;q>=0;q--) Cm=gf_mul(gf_cnot(q),Cm);
  unsigned V[12][4]{},R[12][4]{},rfin[12]{};
  GF12 Mm=gf_id(), Mi=gf_id();
  for(int l=0;l<4;l++){
    for(int q=0;q<12;q++){
      int b=11-q; unsigned v=0;
      for(int j=0;j<12;j++) v|=((Mi.row[j]>>b)&1u)<<j;
      V[l*3+q/4][q&3]=v; R[l*3+q/4][q&3]=Mm.row[b];
    }
    Mm=gf_mul(D,Mm); Mi=gf_mul(Cm,Mi);
  }
  for(int q=0;q<12;q++) rfin[q]=Mm.row[11-q];

  GF12 Sg=gf_id(); Sg.row[1]|=1u<<4; Sg.row[2]|=1u<<5; Sg.row[3]|=1u<<6;

  GF12 Tprev{}, Tprev_inv{};
  for(int m=0;m<6;m++){
    const int p0=2*m, p1=p0+1;
    for(int pp=p0;pp<=p1;pp++) for(int j=0;j<4;j++) for(int i=0;i<4;i++){
      int par=__builtin_popcount(R[pp][j]&V[pp][i])&1;
      if(par!=((i==j)?1:0)) T.ok=false;
    }
    Red S{};
    for(int i=0;i<4;i++){ red_add(S,V[p0][i]); red_add(S,V[p1][i]); }
    for(unsigned x=1;x<4096 && S.n<10;x++) red_add(S,x);
    if(S.n!=10) T.ok=false;
    Red S12=S, RA{}, RB{};
    for(int i=0;i<4;i++){ red_add(RA,V[p0][i]); red_add(RB,V[p1][i]); }
    unsigned B[8]{};
    Red resR{};
    for(int k=0;k<6;k++){
      unsigned pick=0;
      if(m>0){
        unsigned res=(k<4)?(1u<<k):0u;
        for(unsigned hi=(k<4)?0u:1u; hi<256 && !pick; hi++){
          unsigned y=res|(hi<<4);
          unsigned x=gf_apply(Tprev_inv,y);
          if(red_reduce(S,x)) continue;
          if(!red_reduce(RA,x)) continue;
          if(!red_reduce(RB,x)) continue;
          pick=x;
        }
        for(unsigned y=1;y<4096 && !pick;y++){
          unsigned x=gf_apply(Tprev_inv,y);
          if(red_reduce(S,x)) continue;
          if(!red_reduce(RA,x)) continue;
          if(!red_reduce(RB,x)) continue;
          if(k<4){ unsigned rb=y&15u; if(!rb || !red_reduce(resR,rb)) continue; }
          pick=x;
        }
      }
      if(!pick){
        for(unsigned x=1;x<4096 && !pick;x++){
          if(red_reduce(S,x)) continue;
          if(!red_reduce(RA,x)) continue;
          if(!red_reduce(RB,x)) continue;
          pick=x;
        }
      }
      if(!pick){ T.ok=false; pick=1; }
      if(m>0 && k<4){ unsigned rb=gf_apply(Tprev,pick)&15u; if(rb) red_add(resR,rb); }
      red_add(RA,pick); red_add(RB,pick);
      B[k]=pick;
    }
    for(int k=6;k<8;k++){
      unsigned pick=0;
      for(unsigned x=1;x<4096 && !pick;x++) if(red_reduce(S12,x)) pick=x;
      if(!pick){ T.ok=false; pick=1; }
      red_add(S12,pick); B[k]=pick;
    }
    if(S12.n!=12) T.ok=false;
    GF12 Z{};
    for(int i=0;i<12;i++){
      unsigned rr=0;
      for(int k=0;k<4;k++) rr |= ((V[p1][k]>>i)&1u)<<k;
      for(int k=0;k<8;k++) rr |= ((B[k]>>i)&1u)<<(4+k);
      Z.row[i]=rr;
    }
    GF12 Tp=gf_inv(Z);
    { GF12 I2=gf_mul(Tp,Z); for(int i=0;i<12;i++) if(I2.row[i]!=(1u<<i)) T.ok=false; }
    for(int j=0;j<4;j++){
      unsigned m0=0,m1=0;
      for(int k=0;k<8;k++){
        m0 |= (unsigned)(__builtin_popcount(R[p0][j]&B[k])&1)<<k;
        m1 |= (unsigned)(__builtin_popcount(R[p1][j]&B[k])&1)<<k;
      }
      T.pr[m].M0[j]=m0; T.pr[m].M1[j]=m1;
    }
    unsigned zeta[4]{}, gam[4]{};
    for(int i=0;i<4;i++){
      unsigned d=gf_apply(Tp,V[p0][i]);
      if(d>>10) T.ok=false;
      zeta[i]=d&15u; gam[i]=(d>>4)&63u;
    }
    unsigned zmap[16]{}; bool seen[16]{};
    for(int z=0;z<16;z++){
      unsigned zz=0;
      for(int i=0;i<4;i++) if((z>>i)&1) zz^=zeta[i];
      zmap[z]=zz;
      if(seen[zz]) T.ok=false; seen[zz]=true;
    }
    for(int zp=0;zp<16;zp++){
      unsigned src=0;
      for(int z=0;z<16;z++) if(zmap[z]==(unsigned)zp) src=(unsigned)z;
      unsigned gg=0;
      for(int i=0;i<4;i++) if((src>>i)&1) gg^=gam[i];
      T.pr[m].sz[zp]=src; T.pr[m].gx[zp]=gg;
    }
    for(int z=0;z<16;z++){
      unsigned c0=0,c1=0,gg=0,bb=0;
      for(int i=0;i<4;i++){
        if((z>>i)&1){ c0^=V[p0][i]; gg^=gam[i]; }
        if((zmap[z]>>i)&1) c1^=V[p1][i];
      }
      for(int k=0;k<6;k++) if((gg>>k)&1) bb^=B[k];
      if((c0^c1^bb)!=0) T.ok=false;
    }
    if(m>0){
      for(int k=0;k<8;k++) T.pr[m].rB[k]=gf_apply(Tprev,B[k]);
      for(int z=0;z<16;z++){
        unsigned c=0;
        for(int i=0;i<4;i++) if((z>>i)&1) c^=V[p0][i];
        T.pr[m].roff[z]=gf_apply(Tprev,c);
      }
    }
    GF12 Tnew=gf_mul(Sg,Tp), Tnew_inv=gf_mul(Z,Sg);
    { GF12 I2=gf_mul(Tnew,Tnew_inv); for(int i=0;i<12;i++) if(I2.row[i]!=(1u<<i)) T.ok=false; }
    Tprev=Tnew; Tprev_inv=Tnew_inv;
    if(m==5){
      for(int q=0;q<12;q++){
        unsigned u=0,mm=0;
        for(int i=0;i<4;i++) u |= (unsigned)(__builtin_popcount(rfin[q]&V[11][i])&1)<<i;
        for(int k=0;k<8;k++) mm |= (unsigned)(__builtin_popcount(rfin[q]&B[k])&1)<<k;
        T.uq[q]=u; T.mq[q]=mm;
      }
    }
  }
  return T;
}

constexpr AllT hA = makeAll();
static_assert(hA.ok, "GF(2) paired-bpermute table self-check failed");

// ---- packed butterfly: 8 v_pk_fma_f32-class ops per (s0,s1) pair ----
// out0 = A0*X + A1*Xs + B0*Y + B1*Ys ; out1 = A0*Y - A1*Ys - B0*X + B1*Xs
// A0=(ar,ar) A1=(-ai',ai') B0=(br',br') B1=(-bi,bi); ai',br' carry role sign.
// Verified vs r1-validated scalar form term-by-term.
#define GATE_PK(SS,MM,JJ) do { \
    const int _lb = pl + 4*(JJ); \
    const unsigned _sg = ((unsigned)(__popc((MM) & (unsigned)t) & 1)) << 31; \
    const float _ar = __uint_as_float((unsigned)__builtin_amdgcn_readlane((int)cur, _lb+0)); \
    const float _ai = __uint_as_float(((unsigned)__builtin_amdgcn_readlane((int)cur, _lb+1)) ^ _sg); \
    const float _br = __uint_as_float(((unsigned)__builtin_amdgcn_readlane((int)cur, _lb+2)) ^ _sg); \
    const float _bi = __uint_as_float((unsigned)__builtin_amdgcn_readlane((int)cur, _lb+3)); \
    const f2 A0 = {_ar,_ar}, A1 = {-_ai,_ai}, B0 = {_br,_br}, B1 = {-_bi,_bi}; \
    _Pragma("unroll") \
    for (int s0=0; s0<16; ++s0){ \
      if ((s0 >> (JJ)) & 1) continue; \
      const int s1 = s0 | (1<<(JJ)); \
      const f2 X = SS[s0], Y = SS[s1]; \
      const f2 Xs = __builtin_shufflevector(X,X,1,0); \
      const f2 Ys = __builtin_shufflevector(Y,Y,1,0); \
      SS[s0] = __builtin_elementwise_fma(A0,X, \
               __builtin_elementwise_fma(A1,Xs, \
               __builtin_elementwise_fma(B0,Y, B1*Ys))); \
      SS[s1] = __builtin_elementwise_fma(A0,Y, \
               __builtin_elementwise_fma(-A1,Ys, \
               __builtin_elementwise_fma(-B0,X, B1*Xs))); \
    } \
  } while(0)

template<int M>
__device__ __forceinline__ void do_pair(f2 S[16], f2 Sn[16],
                                        unsigned c0, unsigned c1, unsigned c2,
                                        unsigned t)
{
  constexpr PairT P = hA.pr[M];
  // pass p0 = 2M
  { constexpr int ci=(2*M)>>2;
    const unsigned cur=(ci==0)?c0:((ci==1)?c1:c2);
    const int pl=((2*M)&3)<<4;
    GATE_PK(S,P.M0[0],0); GATE_PK(S,P.M0[1],1); GATE_PK(S,P.M0[2],2); GATE_PK(S,P.M0[3],3); }
  // wave-internal transition (r8-validated): dest zp pulls src slot sz from lane t^gx
  { const unsigned t4=t<<2;
    #pragma unroll
    for(int zp=0; zp<16; ++zp){
      const int idx=(int)(t4 ^ (P.gx[zp]<<2));
      Sn[zp].x=__uint_as_float((unsigned)__builtin_amdgcn_ds_bpermute(idx,(int)__float_as_uint(S[P.sz[zp]].x)));
      Sn[zp].y=__uint_as_float((unsigned)__builtin_amdgcn_ds_bpermute(idx,(int)__float_as_uint(S[P.sz[zp]].y)));
    } }
  // pass p1 = 2M+1
  { constexpr int ci=(2*M+1)>>2;
    const unsigned cur=(ci==0)?c0:((ci==1)?c1:c2);
    const int pl=((2*M+1)&3)<<4;
    GATE_PK(Sn,P.M1[0],0); GATE_PK(Sn,P.M1[1],1); GATE_PK(Sn,P.M1[2],2); GATE_PK(Sn,P.M1[3],3); }
}

// r8 exchange verbatim: park Sn into LDS as 8 swizzled b128 bursts.
__device__ __forceinline__ void writeS(const f2 Sn[16], float4* s4, unsigned t)
{
  const unsigned wb = t<<3;
  #pragma unroll
  for(int k=0;k<8;++k)
    s4[wb | ((unsigned)k ^ (t&7u))] =
      make_float4(Sn[2*k].x, Sn[2*k].y, Sn[2*k+1].x, Sn[2*k+1].y);
}

// Un-park a state that has completed pair MP-1 (tables pr[MP]): 16 b64 reads
// at engineered conflict-floor residues.
template<int MP>
__device__ __forceinline__ void readS(f2 S[16], const float2* s2, unsigned t)
{
  constexpr PairT P = hA.pr[MP];
  unsigned base=0;
  #pragma unroll
  for(int k=0;k<8;++k) base ^= ((t>>k)&1u) ? P.rB[k] : 0u;
  #pragma unroll
  for(int z=0;z<16;++z){ float2 v=s2[base ^ P.roff[z]]; S[z].x=v.x; S[z].y=v.y; }
}

__device__ __forceinline__ void initS(f2 S[16], unsigned t)
{
  #pragma unroll
  for(int k=0;k<16;++k){ S[k].x=0.f; S[k].y=0.f; }
  if(t==0) S[0].x=1.0f;
}

// measurement: 16-pt WHT over z (r6-validated) -> 12 signed expval shares
__device__ __forceinline__ void measure(const f2 Sn[16], float acc[12], unsigned t)
{
  float H[16];
  #pragma unroll
  for(int z=0;z<16;++z) H[z]=fmaf(Sn[z].x,Sn[z].x, Sn[z].y*Sn[z].y);
  #pragma unroll
  for(int st=1;st<16;st<<=1){
    #pragma unroll
    for(int z=0;z<16;++z){
      if(z & st) continue;
      float a0=H[z], a1=H[z|st];
      H[z]=a0+a1; H[z|st]=a0-a1;
    }
  }
  #pragma unroll
  for(int q=0;q<12;++q){
    const unsigned ls=((unsigned)(__popc(hA.mq[q]&t)&1))<<31;
    acc[q]=__uint_as_float(__float_as_uint(H[hA.uq[q]])^ls);
  }
}

__global__ void __launch_bounds__(TPB, 4)
qgen(const float* __restrict__ noise,
     const float* __restrict__ W1, const float* __restrict__ b1,
     const float* __restrict__ W2, const float* __restrict__ b2,
     const float* __restrict__ W3, const float* __restrict__ b3,
     const float* __restrict__ W4, const float* __restrict__ b4,
     float* __restrict__ out)
{
  __shared__ float2 sbuf[4096];        // 32 KiB exchange buffer (r8 layout)
  float*  sf=(float*)sbuf;
  float2* s2=(float2*)sbuf;
  float4* s4=(float4*)sbuf;

  const unsigned t = threadIdx.x;
  const int b = blockIdx.x;            // handles batch elements 2b (A), 2b+1 (B)
  const int lane = t & 63;

  // ---- prologue MLP x2 (r3/r6-validated math; coeffs A->[0,192) B->[192,384)
  //      floats, scratch relocated to [448,688) -- disjoint) ----
  #pragma unroll
  for(int e=0;e<2;++e){
    if (t < 12) sf[448+t] = noise[(2*b+e)*12+t];
    __syncthreads();
    if (t < 64){
      float a = b1[t];
      #pragma unroll
      for (int k=0;k<12;++k) a = fmaf(sf[448+k], W1[k*64+t], a);
      sf[464+t] = tanhf(a);
    }
    __syncthreads();
    if (t < 144){
      float a = b2[t];
      #pragma unroll 16
      for (int j=0;j<64;++j) a = fmaf(sf[464+j], W2[j*144+t], a);
      sf[544+t] = a;
    }
    __syncthreads();
    if (t < 48){
      float aa = sf[544+3*t+0]*0.5f, bb = sf[544+3*t+1]*0.5f, c = sf[544+3*t+2]*0.5f;
      float sa,ca,sb,cb,sc2,cc;
      __sincosf(aa,&sa,&ca); __sincosf(bb,&sb,&cb); __sincosf(c,&sc2,&cc);
      float A=cb*ca, B=sb*sa, Cc=sb*ca, Dd=cb*sa;
      s4[e*48+t] = make_float4(fmaf(cc,A,  sc2*B),  fmaf(cc,B, -sc2*A),
                               fmaf(-cc,Cc,-sc2*Dd), fmaf(sc2,Cc,-cc*Dd));
    }
    __syncthreads();
  }
  const unsigned* su=(const unsigned*)sbuf;
  const unsigned cA0=su[lane],     cA1=su[64+lane],  cA2=su[128+lane];
  const unsigned cB0=su[192+lane], cB1=su[256+lane], cB2=su[320+lane];
  __syncthreads();                     // coeff reads done before state writes

  // ---- ping-pong schedule: 12 half-steps, shared S/Sn register frames ----
  // i=2k   (A at pair k): do_pair<k>(cA); read other's parked (pr[k]);  sync; write; sync
  // i=2k+1 (B at pair k): do_pair<k>(cB); read other's parked (pr[k+1]); sync; write; sync
  f2 S[16], Sn[16];

  // i=0 : A pair 0 (nothing parked yet)
  initS(S,t);
  do_pair<0>(S,Sn,cA0,cA1,cA2,t);
  writeS(Sn,s4,t);                     // buffer-free guarded by prologue sync
  __syncthreads();
  // i=1 : B pair 0 ; un-park A (pr[1])
  initS(S,t);
  do_pair<0>(S,Sn,cB0,cB1,cB2,t);
  readS<1>(S,s2,t);
  __syncthreads();
  writeS(Sn,s4,t);
  __syncthreads();

  do_pair<1>(S,Sn,cA0,cA1,cA2,t); readS<1>(S,s2,t); __syncthreads(); writeS(Sn,s4,t); __syncthreads();
  do_pair<1>(S,Sn,cB0,cB1,cB2,t); readS<2>(S,s2,t); __syncthreads(); writeS(Sn,s4,t); __syncthreads();
  do_pair<2>(S,Sn,cA0,cA1,cA2,t); readS<2>(S,s2,t); __syncthreads(); writeS(Sn,s4,t); __syncthreads();
  do_pair<2>(S,Sn,cB0,cB1,cB2,t); readS<3>(S,s2,t); __syncthreads(); writeS(Sn,s4,t); __syncthreads();
  do_pair<3>(S,Sn,cA0,cA1,cA2,t); readS<3>(S,s2,t); __syncthreads(); writeS(Sn,s4,t); __syncthreads();
  do_pair<3>(S,Sn,cB0,cB1,cB2,t); readS<4>(S,s2,t); __syncthreads(); writeS(Sn,s4,t); __syncthreads();
  do_pair<4>(S,Sn,cA0,cA1,cA2,t); readS<4>(S,s2,t); __syncthreads(); writeS(Sn,s4,t); __syncthreads();
  do_pair<4>(S,Sn,cB0,cB1,cB2,t); readS<5>(S,s2,t); __syncthreads(); writeS(Sn,s4,t); __syncthreads();

  // i=10 : A pair 5 ; measure A ; un-park B (pr[5], written at i=9, sync'd)
  do_pair<5>(S,Sn,cA0,cA1,cA2,t);
  float accA[12]; measure(Sn,accA,t);
  readS<5>(S,s2,t);
  // i=11 : B pair 5 ; measure B
  do_pair<5>(S,Sn,cB0,cB1,cB2,t);
  float accB[12]; measure(Sn,accB,t);

  __syncthreads();                     // all exchange reads done -> LDS reusable

  // ---- epilogue: per-wave reduce both elements, then MLP on waves 0/1 ----
  const int wv=t>>6;
  #pragma unroll
  for(int q=0;q<12;++q){
    float v=accA[q];
    #pragma unroll
    for(int off=32;off>0;off>>=1) v += __shfl_down(v,off,64);
    if(lane==0) sf[wv*12+q]=v;
  }
  #pragma unroll
  for(int q=0;q<12;++q){
    float v=accB[q];
    #pragma unroll
    for(int off=32;off>0;off>>=1) v += __shfl_down(v,off,64);
    if(lane==0) sf[100+wv*12+q]=v;
  }
  __syncthreads();
  if(t<12)            sf[64+t]      = sf[t]        +sf[12+t]      +sf[24+t]      +sf[36+t];
  else if(t>=64&&t<76) sf[164+(t-64)]= sf[100+(t-64)]+sf[112+(t-64)]+sf[124+(t-64)]+sf[136+(t-64)];
  __syncthreads();

  if(t<64){            // wave 0: element A (batch 2b)
    float a=b3[t];
    #pragma unroll
    for(int k=0;k<12;++k) a=fmaf(sf[64+k],W3[k*64+t],a);
    float h2=tanhf(a);
    float p0=h2*W4[2*t+0], p1=h2*W4[2*t+1];
    #pragma unroll
    for(int off=32;off>0;off>>=1){ p0+=__shfl_down(p0,off,64); p1+=__shfl_down(p1,off,64); }
    if(lane==0){ out[4*b+0]=p0+b4[0]; out[4*b+1]=p1+b4[1]; }
  } else if(t<128){    // wave 1: element B (batch 2b+1)
    const int t2=t-64;
    float a=b3[t2];
    #pragma unroll
    for(int k=0;k<12;++k) a=fmaf(sf[164+k],W3[k*64+t2],a);
    float h2=tanhf(a);
    float p0=h2*W4[2*t2+0], p1=h2*W4[2*t2+1];
    #pragma unroll
    for(int off=32;off>0;off>>=1){ p0+=__shfl_down(p0,off,64); p1+=__shfl_down(p1,off,64); }
    if(lane==0){ out[4*b+2]=p0+b4[0]; out[4*b+3]=p1+b4[1]; }
  }
}

extern "C" void kernel_launch(void* const* d_in, const int* in_sizes, int n_in,
                              void* d_out, int out_size, void* d_ws, size_t ws_size,
                              hipStream_t stream)
{
  const float* noise=(const float*)d_in[0];
  const float* W1=(const float*)d_in[1];
  const float* b1=(const float*)d_in[2];
  const float* W2=(const float*)d_in[3];
  const float* b2=(const float*)d_in[4];
  const float* W3=(const float*)d_in[5];
  const float* b3=(const float*)d_in[6];
  const float* W4=(const float*)d_in[7];
  const float* b4=(const float*)d_in[8];
  float* out=(float*)d_out;
  const int batch=in_sizes[0]/NQ;   // 4096
  qgen<<<batch/2,TPB,0,stream>>>(noise,W1,b1,W2,b2,W3,b3,W4,b4,out);
}